// Round 10
// baseline (372.788 us; speedup 1.0000x reference)
//
#include <hip/hip_runtime.h>
#include <math.h>

#define BLOCK 256
#define NPB 64         // samples per block
#define NPAIRS (NPB/2) // 32 packed sample pairs

#if __has_builtin(__builtin_amdgcn_exp2f)
#define EXP2F(x) __builtin_amdgcn_exp2f(x)
#else
#define EXP2F(x) exp2f(x)
#endif

typedef float v2f __attribute__((ext_vector_type(2)));
typedef float v4f __attribute__((ext_vector_type(4)));

// out[b,m] = coefN * sum_n exp2(a_n*px + b_n*py - c_n - q_m)
//   a = 2t*sx, b = 2t*sy, c = t*|s|^2, q_m = t*|p_m|^2  (arg always <= 0)
//
// R9 measured 27.4 cyc/exp vs a 21.2 fully-serialized issue model -> ~30%
// residual stalls at 4 waves/SIMD. This round: 8 waves/SIMD
// (__launch_bounds__(256,8), ~35 VGPRs live, MPT=2) so sibling waves cover
// lgkm/trans dependency stalls; ds_reads cut 3->2 per sample-pair by packing
// {a0,a1,b0,b1} as one v4f (ds_read_b128) + {c0,c1} as v2f (ds_read_b64).
__global__ __launch_bounds__(BLOCK, 8) void kde_kernel(
    const float* __restrict__ inputs,   // (B, N, 2)
    const float* __restrict__ points,   // (M, 2)
    float* __restrict__ out,            // (B, M), pre-zeroed
    int N, int M, float t, float t2, float coefN)
{
    const int b   = blockIdx.y;
    const int n0  = blockIdx.x * NPB;
    const int tid = (int)threadIdx.x;

    __shared__ v4f SAB[NPAIRS];         // {a0,a1,b0,b1} per sample pair
    __shared__ v2f SC[NPAIRS];          // {c0,c1}

    if (tid < NPAIRS) {
        // two consecutive samples: (sx0, sy0, sx1, sy1)
        const float4 s2 =
            reinterpret_cast<const float4*>(inputs)[((b * N + n0) >> 1) + tid];
        SAB[tid] = (v4f){t2 * s2.x, t2 * s2.z, t2 * s2.y, t2 * s2.w};
        SC[tid]  = (v2f){t * fmaf(s2.x, s2.x, s2.y * s2.y),
                         t * fmaf(s2.z, s2.z, s2.w * s2.w)};
    }

    const int m0 = tid;
    const int m1 = tid + BLOCK;
    const float2* pts = reinterpret_cast<const float2*>(points);
    const float2 p0 = pts[m0 < M ? m0 : 0];
    const float2 p1 = pts[m1 < M ? m1 : 0];
    const float q0 = t * fmaf(p0.x, p0.x, p0.y * p0.y);
    const float q1 = t * fmaf(p1.x, p1.x, p1.y * p1.y);

    const v2f PX0 = {p0.x, p0.x}, PY0 = {p0.y, p0.y}, NQ0 = {-q0, -q0};
    const v2f PX1 = {p1.x, p1.x}, PY1 = {p1.y, p1.y}, NQ1 = {-q1, -q1};

    __syncthreads();

    v2f acc0 = {0.f, 0.f}, acc1 = {0.f, 0.f};

#pragma unroll
    for (int j = 0; j < NPAIRS; ++j) {
        const v4f ab = SAB[j];          // ds_read_b128
        const v2f c  = SC[j];           // ds_read_b64
        const v2f a  = {ab.x, ab.y};
        const v2f bb = {ab.z, ab.w};
        const v2f k0 = NQ0 - c;
        const v2f k1 = NQ1 - c;
        const v2f w0 = __builtin_elementwise_fma(a, PX0,
                           __builtin_elementwise_fma(bb, PY0, k0));
        const v2f w1 = __builtin_elementwise_fma(a, PX1,
                           __builtin_elementwise_fma(bb, PY1, k1));
        v2f e0, e1;
        e0.x = EXP2F(w0.x); e0.y = EXP2F(w0.y);
        e1.x = EXP2F(w1.x); e1.y = EXP2F(w1.y);
        acc0 += e0;
        acc1 += e1;
    }

    if (m0 < M) atomicAdd(&out[(size_t)b * M + m0], (acc0.x + acc0.y) * coefN);
    if (m1 < M) atomicAdd(&out[(size_t)b * M + m1], (acc1.x + acc1.y) * coefN);
}

extern "C" void kernel_launch(void* const* d_in, const int* in_sizes, int n_in,
                              void* d_out, int out_size, void* d_ws, size_t ws_size,
                              hipStream_t stream) {
    const float* inputs = (const float*)d_in[0];   // (B, N, 2) fp32
    const float* points = (const float*)d_in[1];   // (M, 2) fp32
    float* out = (float*)d_out;                    // (B, M) fp32

    const int M = in_sizes[1] / 2;          // 512
    const int B = out_size / M;             // 128
    const int N = in_sizes[0] / (2 * B);    // 2048

    // Silverman bandwidth, d = 2
    const double h    = pow(4.0 / 4.0, 1.0 / 6.0) * pow((double)N, -1.0 / 6.0);
    const double h2   = h * h;
    const double coef = 1.0 / (2.0 * M_PI * h2);
    const double td   = 0.5 / (h2 * M_LN2);       // exp(-0.5*sq/h^2) = exp2(-t*sq)
    const float  t     = (float)td;
    const float  t2    = (float)(2.0 * td);
    const float  coefN = (float)(coef / (double)N);

    hipMemsetAsync(out, 0, (size_t)out_size * sizeof(float), stream);

    dim3 grid(N / NPB, B);                  // (32, 128) = 4096 blocks
    kde_kernel<<<grid, BLOCK, 0, stream>>>(inputs, points, out,
                                           N, M, t, t2, coefN);
}

// Round 11
// 72.645 us; speedup vs baseline: 5.1316x; 5.1316x over previous
//
#include <hip/hip_runtime.h>
#include <math.h>

#define BLOCK 256
#define NPB 128        // samples per block
#define NPAIRS (NPB/2) // 64 packed sample pairs

#if __has_builtin(__builtin_amdgcn_exp2f)
#define EXP2F(x) __builtin_amdgcn_exp2f(x)
#else
#define EXP2F(x) exp2f(x)
#endif

typedef float v2f __attribute__((ext_vector_type(2)));
typedef float v4f __attribute__((ext_vector_type(4)));

// out[b,m] = coefN * sum_n exp2(a_n*px + b_n*py - c_n - q_m)
//   a = 2t*sx, b = 2t*sy, c = t*|s|^2, q_m = t*|p_m|^2  (arg always <= 0)
//
// R10 post-mortem: __launch_bounds__(256,8)'s 64-VGPR cap + full unroll made
// the allocator drop to a 32-reg tier and spill ~570 B/thread to scratch
// (574/598 MB HBM traffic, 358 us). This round reaches 8 waves/SIMD by
// LOWERING REAL REGISTER DEMAND instead of capping: no min-waves bound,
// MPT=2 (live state ~26 regs), unroll 4 (~24 in-flight LDS regs) -> expected
// 40-56 VGPR allocation -> 8 waves/SIMD naturally (2048 blocks = 8/CU x 4
// waves = 32 waves/CU). NPB=128 halves per-block staging/sync overhead vs R9.
// Issue model: per j-pair 4 exp(16cy) + 8 pk(2cy) + 2 ds(2cy) = 21 cyc/exp.
__global__ __launch_bounds__(BLOCK) void kde_kernel(
    const float* __restrict__ inputs,   // (B, N, 2)
    const float* __restrict__ points,   // (M, 2)
    float* __restrict__ out,            // (B, M), pre-zeroed
    int N, int M, float t, float t2, float coefN)
{
    const int b   = blockIdx.y;
    const int n0  = blockIdx.x * NPB;
    const int tid = (int)threadIdx.x;

    __shared__ v4f SAB[NPAIRS];         // {a0,a1,b0,b1} per sample pair (1 KB)
    __shared__ v2f SC[NPAIRS];          // {c0,c1} (512 B)

    if (tid < NPAIRS) {
        // two consecutive samples: (sx0, sy0, sx1, sy1)
        const float4 s2 =
            reinterpret_cast<const float4*>(inputs)[((b * N + n0) >> 1) + tid];
        SAB[tid] = (v4f){t2 * s2.x, t2 * s2.z, t2 * s2.y, t2 * s2.w};
        SC[tid]  = (v2f){t * fmaf(s2.x, s2.x, s2.y * s2.y),
                         t * fmaf(s2.z, s2.z, s2.w * s2.w)};
    }

    const int m0 = tid;
    const int m1 = tid + BLOCK;
    const float2* pts = reinterpret_cast<const float2*>(points);
    const float2 p0 = pts[m0 < M ? m0 : 0];
    const float2 p1 = pts[m1 < M ? m1 : 0];
    const float q0 = t * fmaf(p0.x, p0.x, p0.y * p0.y);
    const float q1 = t * fmaf(p1.x, p1.x, p1.y * p1.y);

    const v2f PX0 = {p0.x, p0.x}, PY0 = {p0.y, p0.y}, NQ0 = {-q0, -q0};
    const v2f PX1 = {p1.x, p1.x}, PY1 = {p1.y, p1.y}, NQ1 = {-q1, -q1};

    __syncthreads();

    v2f acc0 = {0.f, 0.f}, acc1 = {0.f, 0.f};

#pragma unroll 4
    for (int j = 0; j < NPAIRS; ++j) {
        const v4f ab = SAB[j];          // ds_read_b128 (broadcast)
        const v2f c  = SC[j];           // ds_read_b64
        const v2f a  = {ab.x, ab.y};
        const v2f bb = {ab.z, ab.w};
        const v2f k0 = NQ0 - c;         // v_pk_add (neg modifier)
        const v2f k1 = NQ1 - c;
        const v2f w0 = __builtin_elementwise_fma(a, PX0,
                           __builtin_elementwise_fma(bb, PY0, k0));
        const v2f w1 = __builtin_elementwise_fma(a, PX1,
                           __builtin_elementwise_fma(bb, PY1, k1));
        v2f e0, e1;
        e0.x = EXP2F(w0.x); e0.y = EXP2F(w0.y);
        e1.x = EXP2F(w1.x); e1.y = EXP2F(w1.y);
        acc0 += e0;                     // v_pk_add_f32
        acc1 += e1;
    }

    if (m0 < M) atomicAdd(&out[(size_t)b * M + m0], (acc0.x + acc0.y) * coefN);
    if (m1 < M) atomicAdd(&out[(size_t)b * M + m1], (acc1.x + acc1.y) * coefN);
}

extern "C" void kernel_launch(void* const* d_in, const int* in_sizes, int n_in,
                              void* d_out, int out_size, void* d_ws, size_t ws_size,
                              hipStream_t stream) {
    const float* inputs = (const float*)d_in[0];   // (B, N, 2) fp32
    const float* points = (const float*)d_in[1];   // (M, 2) fp32
    float* out = (float*)d_out;                    // (B, M) fp32

    const int M = in_sizes[1] / 2;          // 512
    const int B = out_size / M;             // 128
    const int N = in_sizes[0] / (2 * B);    // 2048

    // Silverman bandwidth, d = 2
    const double h    = pow(4.0 / 4.0, 1.0 / 6.0) * pow((double)N, -1.0 / 6.0);
    const double h2   = h * h;
    const double coef = 1.0 / (2.0 * M_PI * h2);
    const double td   = 0.5 / (h2 * M_LN2);       // exp(-0.5*sq/h^2) = exp2(-t*sq)
    const float  t     = (float)td;
    const float  t2    = (float)(2.0 * td);
    const float  coefN = (float)(coef / (double)N);

    hipMemsetAsync(out, 0, (size_t)out_size * sizeof(float), stream);

    dim3 grid(N / NPB, B);                  // (16, 128) = 2048 blocks
    kde_kernel<<<grid, BLOCK, 0, stream>>>(inputs, points, out,
                                           N, M, t, t2, coefN);
}